// Round 5
// baseline (358.306 us; speedup 1.0000x reference)
//
#include <hip/hip_runtime.h>
#include <stdint.h>

#define NB 131072     // batch
#define MS 32         // samples per block (32 -> 37.4 KB LDS -> 4 blocks/CU)
#define ROWS 264      // shorts per LDS activation row (528 B, 16B-aligned, +4 pad)

typedef __bf16 bf16x8 __attribute__((ext_vector_type(8)));
typedef short  s16x8  __attribute__((ext_vector_type(8)));
typedef float  f32x4  __attribute__((ext_vector_type(4)));
typedef float  f32x2  __attribute__((ext_vector_type(2)));

static __device__ __forceinline__ short f2bf(float f){
  uint32_t u = __builtin_bit_cast(uint32_t, f);
  u = (u + 0x7fffu + ((u >> 16) & 1u)) >> 16;   // RNE
  return (short)(uint16_t)u;
}
static __device__ __forceinline__ float bf2f(short s){
  uint32_t u = ((uint32_t)(uint16_t)s) << 16;
  return __builtin_bit_cast(float, u);
}
static __device__ __forceinline__ float fast_tanh(float x){
  float e = __expf(2.0f * x);
  return 1.0f - 2.0f * __builtin_amdgcn_rcpf(e + 1.0f);
}
static __device__ __forceinline__ float rsum16(float v){
  v += __shfl_xor(v, 1);
  v += __shfl_xor(v, 2);
  v += __shfl_xor(v, 4);
  v += __shfl_xor(v, 8);
  return v;
}

// ---- GEMM core: 32x256 out tile, K=256. A from LDS (bf16), B from global bf16 (L2-hot).
// Wave w computes cols [64w, 64w+64). Layouts (m89/m92-verified):
//   A row=l&15, k=(l>>4)*8+e;  B col=l&15, k=(l>>4)*8+e;  D col=l&15, row=(l>>4)*4+r.
static __device__ __forceinline__ void gemm_core(
    const short* bufA_, const short* __restrict__ Wb,
    int w, int lm, int q, f32x4 acc[2][4])
{
#pragma unroll
  for (int mi=0;mi<2;mi++)
#pragma unroll
    for (int nj=0;nj<4;nj++)
      acc[mi][nj] = (f32x4){0.f,0.f,0.f,0.f};
  const short* ap = bufA_ + lm*ROWS + q*8;
  const short* bp = Wb + (64*w + lm)*256 + q*8;
#pragma unroll
  for (int ks=0; ks<8; ++ks){
    bf16x8 af[2], bfr[4];
#pragma unroll
    for (int mi=0;mi<2;mi++)
      af[mi] = *(const bf16x8*)(ap + 16*mi*ROWS + 32*ks);
#pragma unroll
    for (int nj=0;nj<4;nj++)
      bfr[nj] = *(const bf16x8*)(bp + 16*nj*256 + 32*ks);
#pragma unroll
    for (int mi=0;mi<2;mi++)
#pragma unroll
      for (int nj=0;nj<4;nj++)
        acc[mi][nj] = __builtin_amdgcn_mfma_f32_16x16x32_bf16(af[mi], bfr[nj], acc[mi][nj], 0, 0, 0);
  }
}

// ---- stage: act1 = tanh(x*W1^T + b1) -> bf16 LDS tile [32][256] (stride ROWS)
// thread: s = tid&31 (sample/row), kg = tid>>5 (k-group), 4 iters cover all 32 k-chunks
static __device__ __forceinline__ void stage_act(
    int tid, const float* __restrict__ W1, const float* __restrict__ b1,
    float x0, float x1, short* buf)
{
  const int s  = tid & 31;
  const int kg = tid >> 5;
#pragma unroll
  for (int it=0; it<4; ++it){
    const int k0 = (kg + 8*it) * 8;
    f32x4 wa = *(const f32x4*)(W1 + k0*2);
    f32x4 wb = *(const f32x4*)(W1 + k0*2 + 4);
    f32x4 wc = *(const f32x4*)(W1 + k0*2 + 8);
    f32x4 wd = *(const f32x4*)(W1 + k0*2 + 12);
    f32x4 ba = *(const f32x4*)(b1 + k0);
    f32x4 bb = *(const f32x4*)(b1 + k0 + 4);
    s16x8 p;
    p[0] = f2bf(fast_tanh(x0*wa.x + x1*wa.y + ba.x));
    p[1] = f2bf(fast_tanh(x0*wa.z + x1*wa.w + ba.y));
    p[2] = f2bf(fast_tanh(x0*wb.x + x1*wb.y + ba.z));
    p[3] = f2bf(fast_tanh(x0*wb.z + x1*wb.w + ba.w));
    p[4] = f2bf(fast_tanh(x0*wc.x + x1*wc.y + bb.x));
    p[5] = f2bf(fast_tanh(x0*wc.z + x1*wc.w + bb.y));
    p[6] = f2bf(fast_tanh(x0*wd.x + x1*wd.y + bb.z));
    p[7] = f2bf(fast_tanh(x0*wd.z + x1*wd.w + bb.w));
    *(s16x8*)(buf + s*ROWS + k0) = p;
  }
}

// ---- fwd epilogue: act2 = tanh(acc+b2); write derivative-weighted "d" to bufB (GEMM2 A-operand);
// row-reduce (V: sum act2^2, H: sum W3*act2) into rs[w][srow].
template<int ISH>
static __device__ __forceinline__ void epi_fwd(
    f32x4 acc[2][4], const float* __restrict__ b2, const float* __restrict__ W3,
    short* bufB_, int w, int lm, int q, float* __restrict__ rs)
{
  float b2v[4], w3v[4];
#pragma unroll
  for (int nj=0;nj<4;nj++){
    const int h = 64*w + 16*nj + lm;
    b2v[nj] = b2[h];
    w3v[nj] = ISH ? W3[h] : 0.f;
  }
#pragma unroll
  for (int mi=0;mi<2;mi++){
#pragma unroll
    for (int r=0;r<4;r++){
      const int srow = 16*mi + 4*q + r;
      float part = 0.f;
#pragma unroll
      for (int nj=0;nj<4;nj++){
        const int h = 64*w + 16*nj + lm;
        const float t = fast_tanh(acc[mi][nj][r] + b2v[nj]);
        float d;
        if (ISH){ part += w3v[nj]*t; d = w3v[nj]*(1.f - t*t); }
        else    { part += t*t;       d = t*(1.f - t*t); }
        bufB_[srow*ROWS + h] = f2bf(d);
      }
      const float tot = rsum16(part);
      if (lm == 0) rs[w*MS + srow] = tot;
    }
  }
}

// ---- bwd epilogue (u folded): acc = t[s][kc];
// g = sum_kc t*(1-act1^2)*(W1[kc,0]*p0[s] + W1[kc,1]*p1[s]) -> gs[w][srow]
// where p = (f0, f1+u). For H this is Hdot/(1-H^2), fixed up in combine.
static __device__ __forceinline__ void epi_bwd(
    f32x4 acc[2][4], const short* bufA_, const float* __restrict__ W1,
    int w, int lm, int q, const float* __restrict__ psv, float* __restrict__ gsred)
{
  f32x2 w1v[4];
  int kc[4];
#pragma unroll
  for (int nj=0;nj<4;nj++){
    kc[nj] = 64*w + 16*nj + lm;
    w1v[nj] = *(const f32x2*)(W1 + 2*kc[nj]);
  }
#pragma unroll
  for (int mi=0;mi<2;mi++){
#pragma unroll
    for (int r=0;r<4;r++){
      const int srow = 16*mi + 4*q + r;
      const f32x2 p = *(const f32x2*)(psv + 2*srow);
      float g = 0.f;
#pragma unroll
      for (int nj=0;nj<4;nj++){
        const float v1 = bf2f(bufA_[srow*ROWS + kc[nj]]);
        const float fac = acc[mi][nj][r] * (1.f - v1*v1);
        g += fac * (w1v[nj].x * p.x + w1v[nj].y * p.y);
      }
      const float t0 = rsum16(g);
      if (lm == 0) gsred[w*MS + srow] = t0;
    }
  }
}

__global__ __launch_bounds__(256, 4)
void fused(const float* __restrict__ x,
           const float* __restrict__ VW1, const float* __restrict__ Vb1, const float* __restrict__ Vb2,
           const float* __restrict__ HW1, const float* __restrict__ Hb1, const float* __restrict__ Hb2,
           const float* __restrict__ HW3, const float* __restrict__ Hb3,
           const float* __restrict__ uW1, const float* __restrict__ ub1,
           const float* __restrict__ uW2, const float* __restrict__ ub2,
           const short* __restrict__ VW2bf, const short* __restrict__ VW2T,
           const short* __restrict__ HW2bf, const short* __restrict__ HW2T,
           float* __restrict__ out)
{
  __shared__ __attribute__((aligned(16))) short bufA[MS*ROWS];
  __shared__ __attribute__((aligned(16))) short bufB[MS*ROWS];
  __shared__ float xs[MS][2];
  __shared__ float psv[MS][2];      // (f0, f1+u) per sample
  __shared__ float redu_u[8][MS];   // u-net partials
  __shared__ float rV[4][MS], gV[4][MS], rH[4][MS], gH[4][MS];

  const int tid = (int)threadIdx.x;
  const int w = tid >> 6, l = tid & 63, lm = l & 15, q = l >> 4;
  const int s0 = (int)blockIdx.x * MS;

  if (tid < 2*MS) ((float*)xs)[tid] = x[s0*2 + tid];
  __syncthreads();

  const float x0 = xs[tid & 31][0], x1 = xs[tid & 31][1];

  f32x4 acc[2][4];

  // ---- u-net partials (group g covers 32 h values) + V act1 staging (independent)
  {
    float up = 0.f;
    const int g = tid >> 5;
    const int h0 = 32 * g;
#pragma unroll 8
    for (int i=0;i<32;i++){
      const int h = h0 + i;
      up += uW2[h] * fast_tanh(x0*uW1[2*h] + x1*uW1[2*h+1] + ub1[h]);
    }
    redu_u[g][tid & 31] = up;
  }
  stage_act(tid, VW1, Vb1, x0, x1, bufA);
  __syncthreads();

  // ---- finalize u -> psv, write u output (tid<MS)
  if (tid < MS){
    const int s = tid;
    float us = 0.f;
#pragma unroll
    for (int j=0;j<8;j++) us += redu_u[j][s];
    const float u = fast_tanh(us + ub2[0]);
    const float xx0 = xs[s][0], xx1 = xs[s][1];
    psv[s][0] = xx1;                          // f0
    psv[s][1] = -sinf(xx0) - 0.1f*xx1 + u;    // f1 + u
    out[s0 + s] = u;
  }
  // NOTE: psv is read only after the next __syncthreads() (inside V epi_bwd) — safe.

  // ================= V path =================
  gemm_core(bufA, VW2bf, w, lm, q, acc);
  epi_fwd<0>(acc, Vb2, (const float*)nullptr, bufB, w, lm, q, &rV[0][0]);
  __syncthreads();
  gemm_core(bufB, VW2T, w, lm, q, acc);
  epi_bwd(acc, bufA, VW1, w, lm, q, &psv[0][0], &gV[0][0]);
  __syncthreads();

  // ================= H path =================
  stage_act(tid, HW1, Hb1, x0, x1, bufA);
  __syncthreads();
  gemm_core(bufA, HW2bf, w, lm, q, acc);
  epi_fwd<1>(acc, Hb2, HW3, bufB, w, lm, q, &rH[0][0]);
  __syncthreads();
  gemm_core(bufB, HW2T, w, lm, q, acc);
  epi_bwd(acc, bufA, HW1, w, lm, q, &psv[0][0], &gH[0][0]);
  __syncthreads();

  // ================= final combine =================
  if (tid < MS){
    const int s = tid;
    float sv=0.f, vd=0.f, hp=0.f, hd=0.f;
#pragma unroll
    for (int j=0;j<4;j++){
      sv += rV[j][s]; vd += gV[j][s];
      hp += rH[j][s]; hd += gH[j][s];
    }
    const float V  = 0.5f * sv;
    const float H  = fast_tanh(hp + Hb3[0]);
    const float Hdot = (1.f - H*H) * hd;
    const int gs = s0 + s;
    out[NB + gs]   = V;
    out[2*NB + gs] = vd;     // Vdot (u already folded)
    out[3*NB + gs] = H;
    out[4*NB + gs] = Hdot;
  }
}

// ---- pre-kernel: fp32 weights -> bf16 row-major + bf16 transposed copies in d_ws
__global__ __launch_bounds__(256)
void cvt_w(const float* __restrict__ VW2, const float* __restrict__ HW2, short* __restrict__ ws)
{
  __shared__ short t[64][65];
  const int bx   = (int)blockIdx.x;       // 0..31
  const int m    = bx >> 4;               // 0=V, 1=H
  const int tile = bx & 15;
  const int tr = tile >> 2, tc = tile & 3;
  const float* __restrict__ src = m ? HW2 : VW2;
  short* __restrict__ dN = ws + m * 131072;
  short* __restrict__ dT = dN + 65536;
  const int tid = (int)threadIdx.x;
  const int ri = tid >> 2;                // 0..63 local row
  const int cc = (tid & 3) * 16;          // local col chunk
  const int gr = tr*64 + ri;
#pragma unroll
  for (int j=0;j<16;j++){
    const int gc = tc*64 + cc + j;
    const short b = f2bf(src[gr*256 + gc]);
    dN[gr*256 + gc] = b;
    t[cc + j][ri] = b;
  }
  __syncthreads();
  const int cr = tid >> 2;                // local transposed row (= source col)
#pragma unroll
  for (int j=0;j<16;j++){
    const int sr = cc + j;                // source row local
    dT[(tc*64 + cr)*256 + tr*64 + sr] = t[cr][sr];
  }
}

extern "C" void kernel_launch(void* const* d_in, const int* in_sizes, int n_in,
                              void* d_out, int out_size, void* d_ws, size_t ws_size,
                              hipStream_t stream)
{
  const float* x   = (const float*)d_in[0];
  const float* VW1 = (const float*)d_in[1];
  const float* Vb1 = (const float*)d_in[2];
  const float* VW2 = (const float*)d_in[3];
  const float* Vb2 = (const float*)d_in[4];
  const float* HW1 = (const float*)d_in[5];
  const float* Hb1 = (const float*)d_in[6];
  const float* HW2 = (const float*)d_in[7];
  const float* Hb2 = (const float*)d_in[8];
  const float* HW3 = (const float*)d_in[9];
  const float* Hb3 = (const float*)d_in[10];
  const float* uW1 = (const float*)d_in[11];
  const float* ub1 = (const float*)d_in[12];
  const float* uW2 = (const float*)d_in[13];
  const float* ub2 = (const float*)d_in[14];

  short* wsbf = (short*)d_ws;             // needs 4*65536*2 = 512 KB of d_ws

  cvt_w<<<32, 256, 0, stream>>>(VW2, HW2, wsbf);
  fused<<<NB/MS, 256, 0, stream>>>(x, VW1, Vb1, Vb2, HW1, Hb1, Hb2, HW3, Hb3,
                                   uW1, ub1, uW2, ub2,
                                   wsbf, wsbf + 65536, wsbf + 131072, wsbf + 196608,
                                   (float*)d_out);
}

// Round 6
// 277.657 us; speedup vs baseline: 1.2905x; 1.2905x over previous
//
#include <hip/hip_runtime.h>
#include <stdint.h>

#define NB 131072     // batch
#define MS 64         // samples per block
#define NT 512        // 8 waves; each wave owns a 32-col slice
#define ROWS 264      // shorts per LDS activation row (528 B, 16B-aligned)

typedef __bf16 bf16x8 __attribute__((ext_vector_type(8)));
typedef short  s16x8  __attribute__((ext_vector_type(8)));
typedef float  f32x4  __attribute__((ext_vector_type(4)));
typedef float  f32x2  __attribute__((ext_vector_type(2)));

static __device__ __forceinline__ short f2bf(float f){
  uint32_t u = __builtin_bit_cast(uint32_t, f);
  u = (u + 0x7fffu + ((u >> 16) & 1u)) >> 16;   // RNE
  return (short)(uint16_t)u;
}
static __device__ __forceinline__ float bf2f(short s){
  uint32_t u = ((uint32_t)(uint16_t)s) << 16;
  return __builtin_bit_cast(float, u);
}
static __device__ __forceinline__ float fast_tanh(float x){
  float e = __expf(2.0f * x);
  return 1.0f - 2.0f * __builtin_amdgcn_rcpf(e + 1.0f);
}
static __device__ __forceinline__ float rsum16(float v){
  v += __shfl_xor(v, 1);
  v += __shfl_xor(v, 2);
  v += __shfl_xor(v, 4);
  v += __shfl_xor(v, 8);
  return v;
}

// ---- GEMM core: 64x256 out tile split over 8 waves (32 cols each), K=256.
// A from LDS (bf16), B from global bf16 (L2-hot). Layouts (m89/m92-verified):
//   A row=l&15, k=(l>>4)*8+e;  B col=l&15, k=(l>>4)*8+e;  D col=l&15, row=(l>>4)*4+r.
static __device__ __forceinline__ void gemm_core(
    const short* bufA_, const short* __restrict__ Wb,
    int w, int lm, int q, f32x4 acc[4][2])
{
#pragma unroll
  for (int mi=0;mi<4;mi++)
#pragma unroll
    for (int nj=0;nj<2;nj++)
      acc[mi][nj] = (f32x4){0.f,0.f,0.f,0.f};
  const short* ap = bufA_ + lm*ROWS + q*8;
  const short* bp = Wb + (32*w + lm)*256 + q*8;
#pragma unroll
  for (int ks=0; ks<8; ++ks){
    bf16x8 af[4], bfr[2];
#pragma unroll
    for (int mi=0;mi<4;mi++)
      af[mi] = *(const bf16x8*)(ap + 16*mi*ROWS + 32*ks);
#pragma unroll
    for (int nj=0;nj<2;nj++)
      bfr[nj] = *(const bf16x8*)(bp + 16*nj*256 + 32*ks);
#pragma unroll
    for (int mi=0;mi<4;mi++)
#pragma unroll
      for (int nj=0;nj<2;nj++)
        acc[mi][nj] = __builtin_amdgcn_mfma_f32_16x16x32_bf16(af[mi], bfr[nj], acc[mi][nj], 0, 0, 0);
  }
}

// ---- stage: act1 = tanh(x*W1^T + b1) -> bf16 LDS tile [64][256] (stride ROWS)
// thread: s = tid&63 (sample/row), kg = tid>>6 (0..7), 4 iters cover 32 k-chunks
static __device__ __forceinline__ void stage_act(
    int tid, const float* __restrict__ W1, const float* __restrict__ b1,
    float x0, float x1, short* buf)
{
  const int s  = tid & 63;
  const int kg = tid >> 6;
#pragma unroll
  for (int it=0; it<4; ++it){
    const int k0 = (kg + 8*it) * 8;
    f32x4 wa = *(const f32x4*)(W1 + k0*2);
    f32x4 wb = *(const f32x4*)(W1 + k0*2 + 4);
    f32x4 wc = *(const f32x4*)(W1 + k0*2 + 8);
    f32x4 wd = *(const f32x4*)(W1 + k0*2 + 12);
    f32x4 ba = *(const f32x4*)(b1 + k0);
    f32x4 bb = *(const f32x4*)(b1 + k0 + 4);
    s16x8 p;
    p[0] = f2bf(fast_tanh(x0*wa.x + x1*wa.y + ba.x));
    p[1] = f2bf(fast_tanh(x0*wa.z + x1*wa.w + ba.y));
    p[2] = f2bf(fast_tanh(x0*wb.x + x1*wb.y + ba.z));
    p[3] = f2bf(fast_tanh(x0*wb.z + x1*wb.w + ba.w));
    p[4] = f2bf(fast_tanh(x0*wc.x + x1*wc.y + bb.x));
    p[5] = f2bf(fast_tanh(x0*wc.z + x1*wc.w + bb.y));
    p[6] = f2bf(fast_tanh(x0*wd.x + x1*wd.y + bb.z));
    p[7] = f2bf(fast_tanh(x0*wd.z + x1*wd.w + bb.w));
    *(s16x8*)(buf + s*ROWS + k0) = p;
  }
}

// ---- fwd epilogue: act2 = tanh(acc+b2); write derivative-weighted "d" to bufB;
// row-reduce (V: sum act2^2, H: sum W3*act2) into rs[w][srow].
template<int ISH>
static __device__ __forceinline__ void epi_fwd(
    f32x4 acc[4][2], const float* __restrict__ b2, const float* __restrict__ W3,
    short* bufB_, int w, int lm, int q, float* __restrict__ rs)
{
  float b2v[2], w3v[2];
#pragma unroll
  for (int nj=0;nj<2;nj++){
    const int h = 32*w + 16*nj + lm;
    b2v[nj] = b2[h];
    w3v[nj] = ISH ? W3[h] : 0.f;
  }
#pragma unroll
  for (int mi=0;mi<4;mi++){
#pragma unroll
    for (int r=0;r<4;r++){
      const int srow = 16*mi + 4*q + r;
      float part = 0.f;
#pragma unroll
      for (int nj=0;nj<2;nj++){
        const int h = 32*w + 16*nj + lm;
        const float t = fast_tanh(acc[mi][nj][r] + b2v[nj]);
        float d;
        if (ISH){ part += w3v[nj]*t; d = w3v[nj]*(1.f - t*t); }
        else    { part += t*t;       d = t*(1.f - t*t); }
        bufB_[srow*ROWS + h] = f2bf(d);
      }
      const float tot = rsum16(part);
      if (lm == 0) rs[w*MS + srow] = tot;
    }
  }
}

// ---- bwd epilogue (u folded): g = sum_kc t*(1-act1^2)*(W1[kc,0]*p0 + W1[kc,1]*p1)
static __device__ __forceinline__ void epi_bwd(
    f32x4 acc[4][2], const short* bufA_, const float* __restrict__ W1,
    int w, int lm, int q, const float* __restrict__ psv, float* __restrict__ gsred)
{
  f32x2 w1v[2];
  int kc[2];
#pragma unroll
  for (int nj=0;nj<2;nj++){
    kc[nj] = 32*w + 16*nj + lm;
    w1v[nj] = *(const f32x2*)(W1 + 2*kc[nj]);
  }
#pragma unroll
  for (int mi=0;mi<4;mi++){
#pragma unroll
    for (int r=0;r<4;r++){
      const int srow = 16*mi + 4*q + r;
      const f32x2 p = *(const f32x2*)(psv + 2*srow);
      float g = 0.f;
#pragma unroll
      for (int nj=0;nj<2;nj++){
        const float v1 = bf2f(bufA_[srow*ROWS + kc[nj]]);
        const float fac = acc[mi][nj][r] * (1.f - v1*v1);
        g += fac * (w1v[nj].x * p.x + w1v[nj].y * p.y);
      }
      const float t0 = rsum16(g);
      if (lm == 0) gsred[w*MS + srow] = t0;
    }
  }
}

__global__ __launch_bounds__(NT, 4)
void fused(const float* __restrict__ x,
           const float* __restrict__ VW1, const float* __restrict__ Vb1, const float* __restrict__ Vb2,
           const float* __restrict__ HW1, const float* __restrict__ Hb1, const float* __restrict__ Hb2,
           const float* __restrict__ HW3, const float* __restrict__ Hb3,
           const float* __restrict__ uW1, const float* __restrict__ ub1,
           const float* __restrict__ uW2, const float* __restrict__ ub2,
           const short* __restrict__ VW2bf, const short* __restrict__ VW2T,
           const short* __restrict__ HW2bf, const short* __restrict__ HW2T,
           float* __restrict__ out)
{
  __shared__ __attribute__((aligned(16))) short bufA[MS*ROWS];
  __shared__ __attribute__((aligned(16))) short bufB[MS*ROWS];
  __shared__ float xs[MS][2];
  __shared__ float psv[MS][2];      // (f0, f1+u) per sample
  __shared__ float redu_u[8][MS];   // u-net partials
  __shared__ float rX[8][MS], gX[8][MS];  // reused: V phase then H phase

  const int tid = (int)threadIdx.x;
  const int w = tid >> 6, l = tid & 63, lm = l & 15, q = l >> 4;
  const int s0 = (int)blockIdx.x * MS;

  if (tid < 2*MS) ((float*)xs)[tid] = x[s0*2 + tid];
  __syncthreads();                                   // B1

  const float x0 = xs[tid & 63][0], x1 = xs[tid & 63][1];

  f32x4 acc[4][2];

  // ---- u-net partials (8 groups x 32 h) + V act1 staging (independent)
  {
    float up = 0.f;
    const int g = tid >> 6;
    const int h0 = 32 * g;
#pragma unroll 8
    for (int i=0;i<32;i++){
      const int h = h0 + i;
      up += uW2[h] * fast_tanh(x0*uW1[2*h] + x1*uW1[2*h+1] + ub1[h]);
    }
    redu_u[g][tid & 63] = up;
  }
  stage_act(tid, VW1, Vb1, x0, x1, bufA);
  __syncthreads();                                   // B2

  // ---- finalize u -> psv, write u output
  if (tid < MS){
    const int s = tid;
    float us = 0.f;
#pragma unroll
    for (int j=0;j<8;j++) us += redu_u[j][s];
    const float u = fast_tanh(us + ub2[0]);
    const float xx0 = xs[s][0], xx1 = xs[s][1];
    psv[s][0] = xx1;                          // f0
    psv[s][1] = -sinf(xx0) - 0.1f*xx1 + u;    // f1 + u
    out[s0 + s] = u;
  }

  // ================= V path =================
  gemm_core(bufA, VW2bf, w, lm, q, acc);
  epi_fwd<0>(acc, Vb2, (const float*)nullptr, bufB, w, lm, q, &rX[0][0]);
  __syncthreads();                                   // B3 (also covers psv)
  gemm_core(bufB, VW2T, w, lm, q, acc);
  epi_bwd(acc, bufA, VW1, w, lm, q, &psv[0][0], &gX[0][0]);
  __syncthreads();                                   // B4

  // ---- V outputs (early, so rX/gX can be reused for H) + H act1 staging
  if (tid < MS){
    const int s = tid;
    float sv=0.f, vd=0.f;
#pragma unroll
    for (int j=0;j<8;j++){ sv += rX[j][s]; vd += gX[j][s]; }
    out[NB + s0 + s]   = 0.5f * sv;   // V
    out[2*NB + s0 + s] = vd;          // Vdot (u folded)
  }
  stage_act(tid, HW1, Hb1, x0, x1, bufA);
  __syncthreads();                                   // B5

  // ================= H path =================
  gemm_core(bufA, HW2bf, w, lm, q, acc);
  epi_fwd<1>(acc, Hb2, HW3, bufB, w, lm, q, &rX[0][0]);
  __syncthreads();                                   // B6
  gemm_core(bufB, HW2T, w, lm, q, acc);
  epi_bwd(acc, bufA, HW1, w, lm, q, &psv[0][0], &gX[0][0]);
  __syncthreads();                                   // B7

  if (tid < MS){
    const int s = tid;
    float hp=0.f, hd=0.f;
#pragma unroll
    for (int j=0;j<8;j++){ hp += rX[j][s]; hd += gX[j][s]; }
    const float H  = fast_tanh(hp + Hb3[0]);
    out[3*NB + s0 + s] = H;
    out[4*NB + s0 + s] = (1.f - H*H) * hd;  // Hdot
  }
}

// ---- pre-kernel: fp32 weights -> bf16 row-major + bf16 transposed copies in d_ws
__global__ __launch_bounds__(256)
void cvt_w(const float* __restrict__ VW2, const float* __restrict__ HW2, short* __restrict__ ws)
{
  __shared__ short t[64][65];
  const int bx   = (int)blockIdx.x;       // 0..31
  const int m    = bx >> 4;               // 0=V, 1=H
  const int tile = bx & 15;
  const int tr = tile >> 2, tc = tile & 3;
  const float* __restrict__ src = m ? HW2 : VW2;
  short* __restrict__ dN = ws + m * 131072;
  short* __restrict__ dT = dN + 65536;
  const int tid = (int)threadIdx.x;
  const int ri = tid >> 2;                // 0..63 local row
  const int cc = (tid & 3) * 16;          // local col chunk
  const int gr = tr*64 + ri;
#pragma unroll
  for (int j=0;j<16;j++){
    const int gc = tc*64 + cc + j;
    const short b = f2bf(src[gr*256 + gc]);
    dN[gr*256 + gc] = b;
    t[cc + j][ri] = b;
  }
  __syncthreads();
  const int cr = tid >> 2;                // local transposed row (= source col)
#pragma unroll
  for (int j=0;j<16;j++){
    const int sr = cc + j;                // source row local
    dT[(tc*64 + cr)*256 + tr*64 + sr] = t[cr][sr];
  }
}

extern "C" void kernel_launch(void* const* d_in, const int* in_sizes, int n_in,
                              void* d_out, int out_size, void* d_ws, size_t ws_size,
                              hipStream_t stream)
{
  const float* x   = (const float*)d_in[0];
  const float* VW1 = (const float*)d_in[1];
  const float* Vb1 = (const float*)d_in[2];
  const float* VW2 = (const float*)d_in[3];
  const float* Vb2 = (const float*)d_in[4];
  const float* HW1 = (const float*)d_in[5];
  const float* Hb1 = (const float*)d_in[6];
  const float* HW2 = (const float*)d_in[7];
  const float* Hb2 = (const float*)d_in[8];
  const float* HW3 = (const float*)d_in[9];
  const float* Hb3 = (const float*)d_in[10];
  const float* uW1 = (const float*)d_in[11];
  const float* ub1 = (const float*)d_in[12];
  const float* uW2 = (const float*)d_in[13];
  const float* ub2 = (const float*)d_in[14];

  short* wsbf = (short*)d_ws;             // needs 4*65536*2 = 512 KB of d_ws

  cvt_w<<<32, 256, 0, stream>>>(VW2, HW2, wsbf);
  fused<<<NB/MS, NT, 0, stream>>>(x, VW1, Vb1, Vb2, HW1, Hb1, Hb2, HW3, Hb3,
                                  uW1, ub1, uW2, ub2,
                                  wsbf, wsbf + 65536, wsbf + 131072, wsbf + 196608,
                                  (float*)d_out);
}